// Round 9
// baseline (544.777 us; speedup 1.0000x reference)
//
#include <hip/hip_runtime.h>
#include <hip/hip_bf16.h>
#include <stdint.h>

#define E_DIM 1024
#define H_NUM 16
#define HD_DIM 64
#define B_NUM 8
#define SENG 2048
#define SCHI 1024

typedef __attribute__((ext_vector_type(4))) float f32x4;
typedef __attribute__((ext_vector_type(16))) float f32x16;
typedef __attribute__((ext_vector_type(8))) short bf16x8;
typedef __attribute__((ext_vector_type(8))) unsigned short u16x8;
typedef __attribute__((ext_vector_type(4))) unsigned short u16x4;
typedef __attribute__((ext_vector_type(4))) unsigned int u32x4;

__device__ __forceinline__ unsigned short f2bf(float f) {
  unsigned int u = __builtin_bit_cast(unsigned int, f);
  u = (u + 0x7fffu + ((u >> 16) & 1u)) >> 16;  // RNE
  return (unsigned short)u;
}

__device__ __forceinline__ unsigned int cvtpk_bf16(float a, float b) {
  unsigned int r;
  asm("v_cvt_pk_bf16_f32 %0, %1, %2" : "=v"(r) : "v"(a), "v"(b));
  return r;
}

__device__ __forceinline__ void gload_lds16(const void* g, void* l) {
  __builtin_amdgcn_global_load_lds(
      (const __attribute__((address_space(1))) unsigned int*)g,
      (__attribute__((address_space(3))) unsigned int*)l, 16, 0, 0);
}

// ---------------- f32 -> bf16 cast (8 elems/thread) ----------------
__global__ __launch_bounds__(256) void cast_bf16_k(const float* __restrict__ in,
                                                   unsigned short* __restrict__ out,
                                                   int n) {
  int i = (blockIdx.x * 256 + threadIdx.x) * 8;
  if (i >= n) return;
  float4 a = *(const float4*)(in + i);
  float4 b = *(const float4*)(in + i + 4);
  u16x8 v;
  v[0] = f2bf(a.x); v[1] = f2bf(a.y); v[2] = f2bf(a.z); v[3] = f2bf(a.w);
  v[4] = f2bf(b.x); v[5] = f2bf(b.y); v[6] = f2bf(b.z); v[7] = f2bf(b.w);
  *(u16x8*)(out + i) = v;
}

// ---- Wq/Wk/Wv [H][E][HD] f32 -> WT [N=h*64+d][K=e] bf16 (B^T layout) ----
__global__ __launch_bounds__(256) void pack_w_qkv(const float* __restrict__ w,
                                                  unsigned short* __restrict__ wt) {
  int t = blockIdx.x * 256 + threadIdx.x;  // t = n*1024 + e
  int e = t & 1023;
  int n = t >> 10;
  int h = n >> 6, d = n & 63;
  wt[t] = f2bf(w[(h * E_DIM + e) * HD_DIM + d]);
}

// ---- Wo [E][E] f32 -> WoT [n][k] = Wo[k][n] bf16 ----
__global__ __launch_bounds__(256) void pack_wo(const float* __restrict__ w,
                                               unsigned short* __restrict__ wt) {
  int t = blockIdx.x * 256 + threadIdx.x;  // t = n*1024 + k
  int k = t & 1023;
  int n = t >> 10;
  wt[t] = f2bf(w[k * E_DIM + n]);
}

// ---------------- GEMM: C = A[M,K] * Bt[N,K]^T ----------------
// MODE 1: C f32 row-major [M][N]
// MODE 3: C bf16 into Qh[bh][q][d]    (row=b*SCHI+q,  col=h*64+d)
template <int MODE>
__global__ __launch_bounds__(256) void gemm_bt(const unsigned short* __restrict__ A,
                                               const unsigned short* __restrict__ Bt,
                                               void* __restrict__ Cv,
                                               int M, int N, int K) {
  __shared__ unsigned short As[128 * 32];
  __shared__ unsigned short Bs[128 * 32];
  const int tid = threadIdx.x;
  const int w = tid >> 6, lane = tid & 63;
  const int bm = blockIdx.y, bn = blockIdx.x;
  const int wm = w >> 1, wn = w & 1;
  const int rl = lane & 15, gl = lane >> 4;
  f32x4 acc[4][4] = {};

  const int lr = lane >> 2, lc = lane & 3;  // 16 rows x 4 chunks per wave-load
  const unsigned short* Ag = A + (size_t)(bm * 128 + w * 32 + lr) * K + lc * 8;
  const unsigned short* Bg = Bt + (size_t)(bn * 128 + w * 32 + lr) * K + lc * 8;
  unsigned short* Asw = As + w * 32 * 32;  // wave-uniform LDS base
  unsigned short* Bsw = Bs + w * 32 * 32;

  for (int kt = 0; kt < K; kt += 32) {
    gload_lds16(Ag + kt, Asw);
    gload_lds16(Ag + kt + 16 * K, Asw + 16 * 32);
    gload_lds16(Bg + kt, Bsw);
    gload_lds16(Bg + kt + 16 * K, Bsw + 16 * 32);
    __syncthreads();
    bf16x8 af[4], bfr[4];
#pragma unroll
    for (int mt = 0; mt < 4; ++mt)
      af[mt] = *(const bf16x8*)&As[(wm * 64 + mt * 16 + rl) * 32 + gl * 8];
#pragma unroll
    for (int nt = 0; nt < 4; ++nt)
      bfr[nt] = *(const bf16x8*)&Bs[(wn * 64 + nt * 16 + rl) * 32 + gl * 8];
#pragma unroll
    for (int mt = 0; mt < 4; ++mt)
#pragma unroll
      for (int nt = 0; nt < 4; ++nt)
        acc[mt][nt] =
            __builtin_amdgcn_mfma_f32_16x16x32_bf16(af[mt], bfr[nt], acc[mt][nt], 0, 0, 0);
    __syncthreads();
  }

#pragma unroll
  for (int mt = 0; mt < 4; ++mt)
#pragma unroll
    for (int nt = 0; nt < 4; ++nt) {
      const int row0 = bm * 128 + wm * 64 + mt * 16 + gl * 4;
      const int col = bn * 128 + wn * 64 + nt * 16 + rl;
      if (MODE == 1) {
        float* C = (float*)Cv;
#pragma unroll
        for (int r = 0; r < 4; ++r) C[(size_t)(row0 + r) * N + col] = acc[mt][nt][r];
      } else {  // MODE 3
        unsigned short* Qh = (unsigned short*)Cv;
        const int b = row0 >> 10, q = row0 & 1023;
        const int h = col >> 6, d = col & 63;
        unsigned short* p = Qh + (((size_t)(b * 16 + h) * SCHI + q) * HD_DIM + d);
#pragma unroll
        for (int r = 0; r < 4; ++r) p[(size_t)r * HD_DIM] = f2bf(acc[mt][nt][r]);
      }
    }
}

// ------------- fused K+V projection GEMM (shared A-tile) -------------
// Kh[bh][kk][d] and Vt[bh][d][kk] from one pass over Xe.
// 32 MFMA per barrier-pair (2x the plain kernel), A staging amortized.
__global__ __launch_bounds__(256) void gemm_kv(const unsigned short* __restrict__ A,
                                               const unsigned short* __restrict__ B1t,
                                               const unsigned short* __restrict__ B2t,
                                               unsigned short* __restrict__ Kh,
                                               unsigned short* __restrict__ Vt,
                                               int M, int N, int K) {
  __shared__ unsigned short As[128 * 32];
  __shared__ unsigned short Bs1[128 * 32];
  __shared__ unsigned short Bs2[128 * 32];
  const int tid = threadIdx.x;
  const int w = tid >> 6, lane = tid & 63;
  const int bm = blockIdx.y, bn = blockIdx.x;
  const int wm = w >> 1, wn = w & 1;
  const int rl = lane & 15, gl = lane >> 4;
  f32x4 acc1[4][4] = {};
  f32x4 acc2[4][4] = {};

  const int lr = lane >> 2, lc = lane & 3;
  const unsigned short* Ag = A + (size_t)(bm * 128 + w * 32 + lr) * K + lc * 8;
  const unsigned short* B1g = B1t + (size_t)(bn * 128 + w * 32 + lr) * K + lc * 8;
  const unsigned short* B2g = B2t + (size_t)(bn * 128 + w * 32 + lr) * K + lc * 8;
  unsigned short* Asw = As + w * 32 * 32;
  unsigned short* B1sw = Bs1 + w * 32 * 32;
  unsigned short* B2sw = Bs2 + w * 32 * 32;

  for (int kt = 0; kt < K; kt += 32) {
    gload_lds16(Ag + kt, Asw);
    gload_lds16(Ag + kt + 16 * K, Asw + 16 * 32);
    gload_lds16(B1g + kt, B1sw);
    gload_lds16(B1g + kt + 16 * K, B1sw + 16 * 32);
    gload_lds16(B2g + kt, B2sw);
    gload_lds16(B2g + kt + 16 * K, B2sw + 16 * 32);
    __syncthreads();
    bf16x8 af[4], b1[4], b2[4];
#pragma unroll
    for (int mt = 0; mt < 4; ++mt)
      af[mt] = *(const bf16x8*)&As[(wm * 64 + mt * 16 + rl) * 32 + gl * 8];
#pragma unroll
    for (int nt = 0; nt < 4; ++nt)
      b1[nt] = *(const bf16x8*)&Bs1[(wn * 64 + nt * 16 + rl) * 32 + gl * 8];
#pragma unroll
    for (int nt = 0; nt < 4; ++nt)
      b2[nt] = *(const bf16x8*)&Bs2[(wn * 64 + nt * 16 + rl) * 32 + gl * 8];
#pragma unroll
    for (int mt = 0; mt < 4; ++mt)
#pragma unroll
      for (int nt = 0; nt < 4; ++nt) {
        acc1[mt][nt] =
            __builtin_amdgcn_mfma_f32_16x16x32_bf16(af[mt], b1[nt], acc1[mt][nt], 0, 0, 0);
        acc2[mt][nt] =
            __builtin_amdgcn_mfma_f32_16x16x32_bf16(af[mt], b2[nt], acc2[mt][nt], 0, 0, 0);
      }
    __syncthreads();
  }

#pragma unroll
  for (int mt = 0; mt < 4; ++mt)
#pragma unroll
    for (int nt = 0; nt < 4; ++nt) {
      const int row0 = bm * 128 + wm * 64 + mt * 16 + gl * 4;
      const int col = bn * 128 + wn * 64 + nt * 16 + rl;
      const int b = row0 >> 11, kk = row0 & 2047;
      const int h = col >> 6, d = col & 63;
      // K: [bh][kk][d]
      unsigned short* pk_ = Kh + (((size_t)(b * 16 + h) * SENG + kk) * HD_DIM + d);
#pragma unroll
      for (int r = 0; r < 4; ++r) pk_[(size_t)r * HD_DIM] = f2bf(acc1[mt][nt][r]);
      // V: [bh][d][kk] (pre-transposed), 4 consecutive kk
      u16x4 pv;
#pragma unroll
      for (int r = 0; r < 4; ++r) pv[r] = f2bf(acc2[mt][nt][r]);
      *(u16x4*)(Vt + (size_t)((b * 16 + h) * 64 + d) * SENG + kk) = pv;
    }
}

// ---------------- flash attention, swapped-operand 32x32 ----------------
// grid: (bh=128, qb=8), 256 thr = 4 waves x 32 q-rows. KB=64 keys/iter.
// St = mfma_32x32x16(K_frag, Q_frag): lane owns one q-row (col = lane&31).
// SKIP-MAX softmax: P computed directly with running m (init 0); the sum
// tree (needed for lp anyway) doubles as the overflow guard -- if any
// lane's tile-sum > 2^20 (never on this data; scores*Cs ~ +-3), a uniform
// 2^-32 bump rescales o/lp/P and m += 32. No max tree, no per-iter shfl.
// P -> PV B-frags: 16 cvt_pk + 8 permlane32_swap, zero LDS (r8-verified).
// K/V staging + XOR swizzle + one __syncthreads/iter: r6-verified.
__global__ __launch_bounds__(256) void flash_attn(const unsigned short* __restrict__ Qh,
                                                  const unsigned short* __restrict__ Kh,
                                                  const unsigned short* __restrict__ Vt,
                                                  unsigned short* __restrict__ att) {
  const int bh = blockIdx.x, qb = blockIdx.y;
  const int b = bh >> 4, h = bh & 15;
  const int w = threadIdx.x >> 6, lane = threadIdx.x & 63;
  const int lq = lane & 31, hi = lane >> 5, l7 = lane & 7;

  __shared__ unsigned short Ks[2][4096];  // 2 x 8KB: [key 64][d 64] swizzled
  __shared__ unsigned short Vs[2][4096];  // 2 x 8KB: [d 64][key 64] swizzled

  const unsigned short* Kb = Kh + (size_t)bh * (SENG * HD_DIM);
  const unsigned short* Vb = Vt + (size_t)bh * (HD_DIM * SENG);

  const int q_row = qb * 128 + w * 32 + lq;
  const unsigned short* Qp = Qh + ((size_t)bh * SCHI + q_row) * HD_DIM + hi * 8;
  bf16x8 qf[4];
#pragma unroll
  for (int dc = 0; dc < 4; ++dc) qf[dc] = *(const bf16x8*)(Qp + dc * 16);

  const int lrow = lane >> 3;
  const int scol = ((lane & 7) ^ lrow) << 3;  // u16 units (swizzled col)

  auto stage = [&](int k0, int bufi) {
    if (w < 2) {
      const int c0 = w * 4;
#pragma unroll
      for (int j = 0; j < 4; ++j) {
        const int c = c0 + j;
        gload_lds16(Kb + (size_t)(k0 + c * 8 + lrow) * HD_DIM + scol, &Ks[bufi][c * 512]);
      }
    } else {
      const int c0 = (w - 2) * 4;
#pragma unroll
      for (int j = 0; j < 4; ++j) {
        const int c = c0 + j;
        gload_lds16(Vb + (size_t)(c * 8 + lrow) * SENG + k0 + scol, &Vs[bufi][c * 512]);
      }
    }
  };

  int koff[4];
#pragma unroll
  for (int dc = 0; dc < 4; ++dc)
    koff[dc] = lq * 128 + (((2 * dc + hi) ^ l7) << 4);
  int voff[2][4];
#pragma unroll
  for (int dt = 0; dt < 2; ++dt)
#pragma unroll
    for (int kc = 0; kc < 4; ++kc)
      voff[dt][kc] = (dt * 32 + lq) * 128 + (((2 * kc + hi) ^ l7) << 4);

  f32x16 o[2] = {};
  float m_run = 0.f, lp = 0.f;
  const float Cs = 0.125f * 1.44269504f;  // 1/sqrt(64) * log2(e)

  stage(0, 0);
  __syncthreads();

  for (int it = 0; it < 32; ++it) {
    const int cur = it & 1;
    if (it < 31) stage((it + 1) * 64, cur ^ 1);

    // ---- QK^T (swapped): St[k][q], lane owns col q ----
    const char* KsB = (const char*)Ks[cur];
    f32x16 st0 = {}, st1 = {};
#pragma unroll
    for (int dc = 0; dc < 4; ++dc) {
      bf16x8 kf0 = *(const bf16x8*)(KsB + koff[dc]);
      bf16x8 kf1 = *(const bf16x8*)(KsB + 4096 + koff[dc]);
      st0 = __builtin_amdgcn_mfma_f32_32x32x16_bf16(kf0, qf[dc], st0, 0, 0, 0);
      st1 = __builtin_amdgcn_mfma_f32_32x32x16_bf16(kf1, qf[dc], st1, 0, 0, 0);
    }

    // ---- P directly (skip-max), sum tree = lp update + overflow guard ----
    float p0a[16], p1a[16];
#pragma unroll
    for (int r = 0; r < 16; ++r) p0a[r] = exp2f(fmaf(st0[r], Cs, -m_run));
#pragma unroll
    for (int r = 0; r < 16; ++r) p1a[r] = exp2f(fmaf(st1[r], Cs, -m_run));
    float sbuf[16];
#pragma unroll
    for (int r = 0; r < 16; ++r) sbuf[r] = p0a[r] + p1a[r];
#pragma unroll
    for (int s2 = 8; s2 > 0; s2 >>= 1)
#pragma unroll
      for (int i = 0; i < 8; ++i)
        if (i < s2) sbuf[i] += sbuf[i + s2];
    float t = sbuf[0];
    if (__any(t > 1048576.f)) {  // 2^20: stale-m overflow guard (cold path)
      const float al = 0x1p-32f;
      lp *= al; o[0] *= al; o[1] *= al;
#pragma unroll
      for (int r = 0; r < 16; ++r) { p0a[r] *= al; p1a[r] *= al; }
      t *= al;
      m_run += 32.f;
    }
    lp += t;

    // ---- build PV B-frags in-register: 16 cvt_pk + 8 permlane32_swap ----
    bf16x8 pa[4];
#pragma unroll
    for (int kc = 0; kc < 4; ++kc) {
      const float* ps = (kc < 2) ? p0a : p1a;
      const int base = (kc & 1) * 8;
      unsigned int ua = cvtpk_bf16(ps[base + 0], ps[base + 1]);
      unsigned int ub = cvtpk_bf16(ps[base + 2], ps[base + 3]);
      unsigned int va = cvtpk_bf16(ps[base + 4], ps[base + 5]);
      unsigned int vb = cvtpk_bf16(ps[base + 6], ps[base + 7]);
      asm("v_permlane32_swap_b32 %0, %1" : "+v"(ua), "+v"(va));
      asm("v_permlane32_swap_b32 %0, %1" : "+v"(ub), "+v"(vb));
      pa[kc] = __builtin_bit_cast(bf16x8, (u32x4){ua, ub, va, vb});
    }

    // ---- PV (swapped): O^T[d][q], col = q ----
    const char* VsB = (const char*)Vs[cur];
#pragma unroll
    for (int kc = 0; kc < 4; ++kc) {
#pragma unroll
      for (int dt = 0; dt < 2; ++dt) {
        bf16x8 vf = *(const bf16x8*)(VsB + voff[dt][kc]);
        o[dt] = __builtin_amdgcn_mfma_f32_32x32x16_bf16(vf, pa[kc], o[dt], 0, 0, 0);
      }
    }

    __syncthreads();
  }

  const float lf = lp + __shfl_xor(lp, 32);
  const float inv = 1.0f / lf;
  unsigned short* ob = att + (size_t)(b * SCHI + q_row) * E_DIM + h * HD_DIM;
#pragma unroll
  for (int dt = 0; dt < 2; ++dt)
#pragma unroll
    for (int j = 0; j < 4; ++j) {
      u16x4 pk;
#pragma unroll
      for (int i = 0; i < 4; ++i) pk[i] = f2bf(o[dt][4 * j + i] * inv);
      *(u16x4*)(ob + dt * 32 + 8 * j + 4 * hi) = pk;
    }
}

extern "C" void kernel_launch(void* const* d_in, const int* in_sizes, int n_in,
                              void* d_out, int out_size, void* d_ws, size_t ws_size,
                              hipStream_t stream) {
  const float* eng = (const float*)d_in[0];
  const float* chi = (const float*)d_in[1];
  const float* Wq = (const float*)d_in[2];
  const float* Wk = (const float*)d_in[3];
  const float* Wv = (const float*)d_in[4];
  const float* Wo = (const float*)d_in[5];
  float* out = (float*)d_out;

  char* ws = (char*)d_ws;
  const size_t MB = 1024 * 1024;
  unsigned short* WqT = (unsigned short*)(ws + 0 * MB);    // 2 MB
  unsigned short* WkT = (unsigned short*)(ws + 2 * MB);    // 2 MB
  unsigned short* WvT = (unsigned short*)(ws + 4 * MB);    // 2 MB
  unsigned short* WoT = (unsigned short*)(ws + 6 * MB);    // 2 MB
  unsigned short* Xc = (unsigned short*)(ws + 8 * MB);     // 16 MB (reused as att)
  unsigned short* Xe = (unsigned short*)(ws + 24 * MB);    // 32 MB
  unsigned short* Qh = (unsigned short*)(ws + 56 * MB);    // 16 MB
  unsigned short* Kh = (unsigned short*)(ws + 72 * MB);    // 32 MB
  unsigned short* Vt = (unsigned short*)(ws + 104 * MB);   // 32 MB  -> total 136 MB
  unsigned short* att = Xc;  // Xc dead after Q-GEMM

  pack_w_qkv<<<4096, 256, 0, stream>>>(Wq, WqT);
  pack_w_qkv<<<4096, 256, 0, stream>>>(Wk, WkT);
  pack_w_qkv<<<4096, 256, 0, stream>>>(Wv, WvT);
  pack_wo<<<4096, 256, 0, stream>>>(Wo, WoT);

  cast_bf16_k<<<(B_NUM * SCHI * E_DIM / 8) / 256, 256, 0, stream>>>(chi, Xc, B_NUM * SCHI * E_DIM);
  cast_bf16_k<<<(B_NUM * SENG * E_DIM / 8) / 256, 256, 0, stream>>>(eng, Xe, B_NUM * SENG * E_DIM);

  gemm_bt<3><<<dim3(8, 64), 256, 0, stream>>>(Xc, WqT, (void*)Qh, B_NUM * SCHI, E_DIM, E_DIM);
  gemm_kv<<<dim3(8, 128), 256, 0, stream>>>(Xe, WkT, WvT, Kh, Vt, B_NUM * SENG, E_DIM, E_DIM);

  flash_attn<<<dim3(128, 8), 256, 0, stream>>>(Qh, Kh, Vt, att);

  gemm_bt<1><<<dim3(8, 64), 256, 0, stream>>>(att, WoT, (void*)out, B_NUM * SCHI, E_DIM, E_DIM);
}

// Round 10
// 473.032 us; speedup vs baseline: 1.1517x; 1.1517x over previous
//
#include <hip/hip_runtime.h>
#include <hip/hip_bf16.h>
#include <stdint.h>

#define E_DIM 1024
#define H_NUM 16
#define HD_DIM 64
#define B_NUM 8
#define SENG 2048
#define SCHI 1024

typedef __attribute__((ext_vector_type(4))) float f32x4;
typedef __attribute__((ext_vector_type(16))) float f32x16;
typedef __attribute__((ext_vector_type(8))) short bf16x8;
typedef __attribute__((ext_vector_type(8))) unsigned short u16x8;
typedef __attribute__((ext_vector_type(4))) unsigned short u16x4;
typedef __attribute__((ext_vector_type(4))) unsigned int u32x4;

__device__ __forceinline__ unsigned short f2bf(float f) {
  unsigned int u = __builtin_bit_cast(unsigned int, f);
  u = (u + 0x7fffu + ((u >> 16) & 1u)) >> 16;  // RNE
  return (unsigned short)u;
}

__device__ __forceinline__ unsigned int cvtpk_bf16(float a, float b) {
  unsigned int r;
  asm("v_cvt_pk_bf16_f32 %0, %1, %2" : "=v"(r) : "v"(a), "v"(b));
  return r;
}

__device__ __forceinline__ void gload_lds16(const void* g, void* l) {
  __builtin_amdgcn_global_load_lds(
      (const __attribute__((address_space(1))) unsigned int*)g,
      (__attribute__((address_space(3))) unsigned int*)l, 16, 0, 0);
}

// ---------------- f32 -> bf16 cast (8 elems/thread) ----------------
__global__ __launch_bounds__(256) void cast_bf16_k(const float* __restrict__ in,
                                                   unsigned short* __restrict__ out,
                                                   int n) {
  int i = (blockIdx.x * 256 + threadIdx.x) * 8;
  if (i >= n) return;
  float4 a = *(const float4*)(in + i);
  float4 b = *(const float4*)(in + i + 4);
  u16x8 v;
  v[0] = f2bf(a.x); v[1] = f2bf(a.y); v[2] = f2bf(a.z); v[3] = f2bf(a.w);
  v[4] = f2bf(b.x); v[5] = f2bf(b.y); v[6] = f2bf(b.z); v[7] = f2bf(b.w);
  *(u16x8*)(out + i) = v;
}

// ---- Wq/Wk/Wv [H][E][HD] f32 -> WT [N=h*64+d][K=e] bf16, 3 mats in 1 launch ----
__global__ __launch_bounds__(256) void pack_w_qkv3(const float* __restrict__ wq,
                                                   const float* __restrict__ wk,
                                                   const float* __restrict__ wv,
                                                   unsigned short* __restrict__ oq,
                                                   unsigned short* __restrict__ ok,
                                                   unsigned short* __restrict__ ov) {
  const int m = blockIdx.x >> 12;
  const int t = (blockIdx.x & 4095) * 256 + threadIdx.x;  // t = n*1024 + e
  const float* w = (m == 0) ? wq : (m == 1) ? wk : wv;
  unsigned short* o = (m == 0) ? oq : (m == 1) ? ok : ov;
  int e = t & 1023;
  int n = t >> 10;
  int h = n >> 6, d = n & 63;
  o[t] = f2bf(w[(h * E_DIM + e) * HD_DIM + d]);
}

// ---- Wo [E][E] f32 -> WoT [n][k] = Wo[k][n] bf16 ----
__global__ __launch_bounds__(256) void pack_wo(const float* __restrict__ w,
                                               unsigned short* __restrict__ wt) {
  int t = blockIdx.x * 256 + threadIdx.x;  // t = n*1024 + k
  int k = t & 1023;
  int n = t >> 10;
  wt[t] = f2bf(w[k * E_DIM + n]);
}

// ---------------- GEMM: C = A[M,K] * Bt[N,K]^T, BK=64 ----------------
// 128x128 block, 4 waves (2x2), 64x64 per wave, 32 MFMA per barrier-pair.
// MODE 1: C f32 row-major [M][N]
// MODE 2: C bf16 into Vt[bh][d][kk]   (row=b*SENG+kk, col=h*64+d)
// MODE 3: C bf16 into Qh[bh][q][d]    (row=b*SCHI+q,  col=h*64+d)
// MODE 4: C bf16 into Kh[bh][kk][d]   (row=b*SENG+kk, col=h*64+d)
template <int MODE>
__global__ __launch_bounds__(256) void gemm_bt(const unsigned short* __restrict__ A,
                                               const unsigned short* __restrict__ Bt,
                                               void* __restrict__ Cv,
                                               int M, int N, int K) {
  __shared__ unsigned short As[128 * 64];  // 16 KB
  __shared__ unsigned short Bs[128 * 64];  // 16 KB
  const int tid = threadIdx.x;
  const int w = tid >> 6, lane = tid & 63;
  const int bm = blockIdx.y, bn = blockIdx.x;
  const int wm = w >> 1, wn = w & 1;
  const int rl = lane & 15, gl = lane >> 4;
  f32x4 acc[4][4] = {};

  // staging: wave w owns rows w*32..w*32+31 of A-tile and B-tile.
  // one gload16 covers 8 rows (64 lanes x 16B = 1 KB = 8 x 128B rows).
  const int r8 = lane >> 3, c8 = lane & 7;  // row-in-8, 16B chunk
  const unsigned short* Ag = A + (size_t)(bm * 128 + w * 32 + r8) * K + c8 * 8;
  const unsigned short* Bg = Bt + (size_t)(bn * 128 + w * 32 + r8) * K + c8 * 8;
  unsigned short* Asw = As + w * 32 * 64;  // wave-uniform LDS base
  unsigned short* Bsw = Bs + w * 32 * 64;

  for (int kt = 0; kt < K; kt += 64) {
#pragma unroll
    for (int j = 0; j < 4; ++j) {
      gload_lds16(Ag + kt + (size_t)(8 * j) * K, Asw + j * 512);
      gload_lds16(Bg + kt + (size_t)(8 * j) * K, Bsw + j * 512);
    }
    __syncthreads();
#pragma unroll
    for (int kk = 0; kk < 64; kk += 32) {
      bf16x8 af[4], bfr[4];
#pragma unroll
      for (int mt = 0; mt < 4; ++mt)
        af[mt] = *(const bf16x8*)&As[(wm * 64 + mt * 16 + rl) * 64 + kk + gl * 8];
#pragma unroll
      for (int nt = 0; nt < 4; ++nt)
        bfr[nt] = *(const bf16x8*)&Bs[(wn * 64 + nt * 16 + rl) * 64 + kk + gl * 8];
#pragma unroll
      for (int mt = 0; mt < 4; ++mt)
#pragma unroll
        for (int nt = 0; nt < 4; ++nt)
          acc[mt][nt] =
              __builtin_amdgcn_mfma_f32_16x16x32_bf16(af[mt], bfr[nt], acc[mt][nt], 0, 0, 0);
    }
    __syncthreads();
  }

#pragma unroll
  for (int mt = 0; mt < 4; ++mt)
#pragma unroll
    for (int nt = 0; nt < 4; ++nt) {
      const int row0 = bm * 128 + wm * 64 + mt * 16 + gl * 4;
      const int col = bn * 128 + wn * 64 + nt * 16 + rl;
      if (MODE == 1) {
        float* C = (float*)Cv;
#pragma unroll
        for (int r = 0; r < 4; ++r) C[(size_t)(row0 + r) * N + col] = acc[mt][nt][r];
      } else if (MODE == 2) {
        unsigned short* Vt = (unsigned short*)Cv;
        const int b = row0 >> 11, kk = row0 & 2047;
        const int h = col >> 6, d = col & 63;
        u16x4 pk;
#pragma unroll
        for (int r = 0; r < 4; ++r) pk[r] = f2bf(acc[mt][nt][r]);
        *(u16x4*)(Vt + (size_t)((b * 16 + h) * 64 + d) * SENG + kk) = pk;
      } else if (MODE == 3) {
        unsigned short* Qh = (unsigned short*)Cv;
        const int b = row0 >> 10, q = row0 & 1023;
        const int h = col >> 6, d = col & 63;
        unsigned short* p = Qh + (((size_t)(b * 16 + h) * SCHI + q) * HD_DIM + d);
#pragma unroll
        for (int r = 0; r < 4; ++r) p[(size_t)r * HD_DIM] = f2bf(acc[mt][nt][r]);
      } else {  // MODE 4
        unsigned short* Kh = (unsigned short*)Cv;
        const int b = row0 >> 11, kk = row0 & 2047;
        const int h = col >> 6, d = col & 63;
        unsigned short* p = Kh + (((size_t)(b * 16 + h) * SENG + kk) * HD_DIM + d);
#pragma unroll
        for (int r = 0; r < 4; ++r) p[(size_t)r * HD_DIM] = f2bf(acc[mt][nt][r]);
      }
    }
}

// ---------------- flash attention, swapped-operand 32x32 ----------------
// (r9-verified: passed, absmax 2.441e-4.) grid (bh=128, qb=8), 4 waves x
// 32 q-rows, KB=64. Skip-max softmax with sum-tree overflow guard;
// P->PV frags via cvt_pk + permlane32_swap; one __syncthreads/iter.
__global__ __launch_bounds__(256) void flash_attn(const unsigned short* __restrict__ Qh,
                                                  const unsigned short* __restrict__ Kh,
                                                  const unsigned short* __restrict__ Vt,
                                                  unsigned short* __restrict__ att) {
  const int bh = blockIdx.x, qb = blockIdx.y;
  const int b = bh >> 4, h = bh & 15;
  const int w = threadIdx.x >> 6, lane = threadIdx.x & 63;
  const int lq = lane & 31, hi = lane >> 5, l7 = lane & 7;

  __shared__ unsigned short Ks[2][4096];  // 2 x 8KB: [key 64][d 64] swizzled
  __shared__ unsigned short Vs[2][4096];  // 2 x 8KB: [d 64][key 64] swizzled

  const unsigned short* Kb = Kh + (size_t)bh * (SENG * HD_DIM);
  const unsigned short* Vb = Vt + (size_t)bh * (HD_DIM * SENG);

  const int q_row = qb * 128 + w * 32 + lq;
  const unsigned short* Qp = Qh + ((size_t)bh * SCHI + q_row) * HD_DIM + hi * 8;
  bf16x8 qf[4];
#pragma unroll
  for (int dc = 0; dc < 4; ++dc) qf[dc] = *(const bf16x8*)(Qp + dc * 16);

  const int lrow = lane >> 3;
  const int scol = ((lane & 7) ^ lrow) << 3;  // u16 units (swizzled col)

  auto stage = [&](int k0, int bufi) {
    if (w < 2) {
      const int c0 = w * 4;
#pragma unroll
      for (int j = 0; j < 4; ++j) {
        const int c = c0 + j;
        gload_lds16(Kb + (size_t)(k0 + c * 8 + lrow) * HD_DIM + scol, &Ks[bufi][c * 512]);
      }
    } else {
      const int c0 = (w - 2) * 4;
#pragma unroll
      for (int j = 0; j < 4; ++j) {
        const int c = c0 + j;
        gload_lds16(Vb + (size_t)(c * 8 + lrow) * SENG + k0 + scol, &Vs[bufi][c * 512]);
      }
    }
  };

  int koff[4];
#pragma unroll
  for (int dc = 0; dc < 4; ++dc)
    koff[dc] = lq * 128 + (((2 * dc + hi) ^ l7) << 4);
  int voff[2][4];
#pragma unroll
  for (int dt = 0; dt < 2; ++dt)
#pragma unroll
    for (int kc = 0; kc < 4; ++kc)
      voff[dt][kc] = (dt * 32 + lq) * 128 + (((2 * kc + hi) ^ l7) << 4);

  f32x16 o[2] = {};
  float m_run = 0.f, lp = 0.f;
  const float Cs = 0.125f * 1.44269504f;  // 1/sqrt(64) * log2(e)

  stage(0, 0);
  __syncthreads();

  for (int it = 0; it < 32; ++it) {
    const int cur = it & 1;
    if (it < 31) stage((it + 1) * 64, cur ^ 1);

    // ---- QK^T (swapped): St[k][q], lane owns col q ----
    const char* KsB = (const char*)Ks[cur];
    f32x16 st0 = {}, st1 = {};
#pragma unroll
    for (int dc = 0; dc < 4; ++dc) {
      bf16x8 kf0 = *(const bf16x8*)(KsB + koff[dc]);
      bf16x8 kf1 = *(const bf16x8*)(KsB + 4096 + koff[dc]);
      st0 = __builtin_amdgcn_mfma_f32_32x32x16_bf16(kf0, qf[dc], st0, 0, 0, 0);
      st1 = __builtin_amdgcn_mfma_f32_32x32x16_bf16(kf1, qf[dc], st1, 0, 0, 0);
    }

    // ---- P directly (skip-max), sum tree = lp update + overflow guard ----
    float p0a[16], p1a[16];
#pragma unroll
    for (int r = 0; r < 16; ++r) p0a[r] = exp2f(fmaf(st0[r], Cs, -m_run));
#pragma unroll
    for (int r = 0; r < 16; ++r) p1a[r] = exp2f(fmaf(st1[r], Cs, -m_run));
    float sbuf[16];
#pragma unroll
    for (int r = 0; r < 16; ++r) sbuf[r] = p0a[r] + p1a[r];
#pragma unroll
    for (int s2 = 8; s2 > 0; s2 >>= 1)
#pragma unroll
      for (int i = 0; i < 8; ++i)
        if (i < s2) sbuf[i] += sbuf[i + s2];
    float t = sbuf[0];
    if (__any(t > 1048576.f)) {  // 2^20: stale-m overflow guard (cold path)
      const float al = 0x1p-32f;
      lp *= al; o[0] *= al; o[1] *= al;
#pragma unroll
      for (int r = 0; r < 16; ++r) { p0a[r] *= al; p1a[r] *= al; }
      t *= al;
      m_run += 32.f;
    }
    lp += t;

    // ---- build PV B-frags in-register: 16 cvt_pk + 8 permlane32_swap ----
    bf16x8 pa[4];
#pragma unroll
    for (int kc = 0; kc < 4; ++kc) {
      const float* ps = (kc < 2) ? p0a : p1a;
      const int base = (kc & 1) * 8;
      unsigned int ua = cvtpk_bf16(ps[base + 0], ps[base + 1]);
      unsigned int ub = cvtpk_bf16(ps[base + 2], ps[base + 3]);
      unsigned int va = cvtpk_bf16(ps[base + 4], ps[base + 5]);
      unsigned int vb = cvtpk_bf16(ps[base + 6], ps[base + 7]);
      asm("v_permlane32_swap_b32 %0, %1" : "+v"(ua), "+v"(va));
      asm("v_permlane32_swap_b32 %0, %1" : "+v"(ub), "+v"(vb));
      pa[kc] = __builtin_bit_cast(bf16x8, (u32x4){ua, ub, va, vb});
    }

    // ---- PV (swapped): O^T[d][q], col = q ----
    const char* VsB = (const char*)Vs[cur];
#pragma unroll
    for (int kc = 0; kc < 4; ++kc) {
#pragma unroll
      for (int dt = 0; dt < 2; ++dt) {
        bf16x8 vf = *(const bf16x8*)(VsB + voff[dt][kc]);
        o[dt] = __builtin_amdgcn_mfma_f32_32x32x16_bf16(vf, pa[kc], o[dt], 0, 0, 0);
      }
    }

    __syncthreads();
  }

  const float lf = lp + __shfl_xor(lp, 32);
  const float inv = 1.0f / lf;
  unsigned short* ob = att + (size_t)(b * SCHI + q_row) * E_DIM + h * HD_DIM;
#pragma unroll
  for (int dt = 0; dt < 2; ++dt)
#pragma unroll
    for (int j = 0; j < 4; ++j) {
      u16x4 pk;
#pragma unroll
      for (int i = 0; i < 4; ++i) pk[i] = f2bf(o[dt][4 * j + i] * inv);
      *(u16x4*)(ob + dt * 32 + 8 * j + 4 * hi) = pk;
    }
}

extern "C" void kernel_launch(void* const* d_in, const int* in_sizes, int n_in,
                              void* d_out, int out_size, void* d_ws, size_t ws_size,
                              hipStream_t stream) {
  const float* eng = (const float*)d_in[0];
  const float* chi = (const float*)d_in[1];
  const float* Wq = (const float*)d_in[2];
  const float* Wk = (const float*)d_in[3];
  const float* Wv = (const float*)d_in[4];
  const float* Wo = (const float*)d_in[5];
  float* out = (float*)d_out;

  char* ws = (char*)d_ws;
  const size_t MB = 1024 * 1024;
  unsigned short* WqT = (unsigned short*)(ws + 0 * MB);    // 2 MB
  unsigned short* WkT = (unsigned short*)(ws + 2 * MB);    // 2 MB
  unsigned short* WvT = (unsigned short*)(ws + 4 * MB);    // 2 MB
  unsigned short* WoT = (unsigned short*)(ws + 6 * MB);    // 2 MB
  unsigned short* Xc = (unsigned short*)(ws + 8 * MB);     // 16 MB (reused as att)
  unsigned short* Xe = (unsigned short*)(ws + 24 * MB);    // 32 MB
  unsigned short* Qh = (unsigned short*)(ws + 56 * MB);    // 16 MB
  unsigned short* Kh = (unsigned short*)(ws + 72 * MB);    // 32 MB
  unsigned short* Vt = (unsigned short*)(ws + 104 * MB);   // 32 MB  -> total 136 MB
  unsigned short* att = Xc;  // Xc dead after Q-GEMM

  pack_w_qkv3<<<12288, 256, 0, stream>>>(Wq, Wk, Wv, WqT, WkT, WvT);
  pack_wo<<<4096, 256, 0, stream>>>(Wo, WoT);

  cast_bf16_k<<<(B_NUM * SCHI * E_DIM / 8) / 256, 256, 0, stream>>>(chi, Xc, B_NUM * SCHI * E_DIM);
  cast_bf16_k<<<(B_NUM * SENG * E_DIM / 8) / 256, 256, 0, stream>>>(eng, Xe, B_NUM * SENG * E_DIM);

  gemm_bt<3><<<dim3(8, 64), 256, 0, stream>>>(Xc, WqT, (void*)Qh, B_NUM * SCHI, E_DIM, E_DIM);
  gemm_bt<4><<<dim3(8, 128), 256, 0, stream>>>(Xe, WkT, (void*)Kh, B_NUM * SENG, E_DIM, E_DIM);
  gemm_bt<2><<<dim3(8, 128), 256, 0, stream>>>(Xe, WvT, (void*)Vt, B_NUM * SENG, E_DIM, E_DIM);

  flash_attn<<<dim3(128, 8), 256, 0, stream>>>(Qh, Kh, Vt, att);

  gemm_bt<1><<<dim3(8, 64), 256, 0, stream>>>(att, WoT, (void*)out, B_NUM * SCHI, E_DIM, E_DIM);
}